// Round 5
// baseline (119.481 us; speedup 1.0000x reference)
//
#include <hip/hip_runtime.h>
#include <stdint.h>

// inputs [B=64, T=256, D=1024] f32; tanh -> sequential dual-threshold
// integrate-and-fire scan over T per (b,d). 65536 sequences = 1024 scan
// waves (structural). R5: producer/consumer split — 512-thread blocks:
// waves 0-3 load float4 + tanh + ds_write (parallel work), waves 4-7 run
// the serial v-chain from LDS + store. 8 waves/CU (2/SIMD): more vmem
// issue parallelism (the measured cap: R3/R4 ~6.9 B/cyc/CU vs ~10.2
// achievable) and tanh/scan co-issue per SIMD. No asm vmcnt needed —
// producer waits don't block consumer waves.
#define B_DIM 64
#define T_STEPS 256
#define D_DIM 1024
#define CT 16                   // timesteps per LDS chunk
#define CHUNKS (T_STEPS / CT)   // 16
#define TPB 512
#define DSLICE 256              // d-columns per block

// XLA/Eigen f32 tanh rational approximation — bit-exact vs jnp.tanh
// (verified rounds 1-4: absmax = 0.0). DO NOT change the FMA structure.
__device__ __forceinline__ float xla_tanhf(float x) {
    const float kClamp = 7.90531110763549805f;
    float xc = fminf(fmaxf(x, -kClamp), kClamp);
    float x2 = xc * xc;
    float p = __builtin_fmaf(x2, -2.76076847742355e-16f, 2.00018790482477e-13f);
    p = __builtin_fmaf(x2, p, -8.60467152213735e-11f);
    p = __builtin_fmaf(x2, p, 5.12229709037114e-08f);
    p = __builtin_fmaf(x2, p, 1.48572235717979e-05f);
    p = __builtin_fmaf(x2, p, 6.37261928875436e-04f);
    p = __builtin_fmaf(x2, p, 4.89352455891786e-03f);
    p = xc * p;
    float q = __builtin_fmaf(x2, 1.19825839466702e-06f, 1.18534705686654e-04f);
    q = __builtin_fmaf(x2, q, 2.26843463243900e-03f);
    q = __builtin_fmaf(x2, q, 4.89352518554385e-03f);
    float r = p / q;           // IEEE divide — required for bit-exactness
    return (fabsf(x) < 0.0004f) ? x : r;
}

__global__ __launch_bounds__(TPB)
void spike_scan_kernel(const float* __restrict__ in, float* __restrict__ out) {
    // rates ring buffer: 2 x 16 KB (row t: 256 floats, no padding; consumer
    // reads stride-4B = 2 lanes/bank = conflict-free)
    __shared__ float lds_r[2][CT][DSLICE];

    const int tid = threadIdx.x;
    const int blk = blockIdx.x;          // 0..255
    const int b   = blk >> 2;
    const int d0  = (blk & 3) << 8;      // 256-wide d-slice
    const size_t base = (size_t)b * (T_STEPS * D_DIM) + d0;
    const int wave = tid >> 6;

    if (wave < 4) {
        // ---- producer: wave w owns rows 4w..4w+3 of each chunk ----
        const int lane = tid & 63;
        const int w = wave;
        // lane covers d = d0 + 4*lane .. +3; one float4 load per row:
        // a wave's single dwordx4 instruction covers the full 1KB row.
        const float* gp = in + base + (size_t)(4 * w) * D_DIM + 4 * lane;

        float4 cur[4], nxt[4];
        #pragma unroll
        for (int r = 0; r < 4; ++r)
            cur[r] = *(const float4*)(gp + (size_t)r * D_DIM);

        #pragma unroll 1
        for (int c = 0; c < CHUNKS; ++c) {
            if (c + 1 < CHUNKS) {        // prefetch chunk c+1 (one chunk of slack)
                const float* gn = gp + (size_t)(c + 1) * CT * D_DIM;
                #pragma unroll
                for (int r = 0; r < 4; ++r)
                    nxt[r] = *(const float4*)(gn + (size_t)r * D_DIM);
            }
            const int pp = c & 1;
            #pragma unroll
            for (int r = 0; r < 4; ++r) {
                float4 t4;
                t4.x = xla_tanhf(cur[r].x);
                t4.y = xla_tanhf(cur[r].y);
                t4.z = xla_tanhf(cur[r].z);
                t4.w = xla_tanhf(cur[r].w);
                *(float4*)&lds_r[pp][4 * w + r][4 * lane] = t4;  // ds_write_b128
            }
            __syncthreads();             // barrier c: chunk c staged; consumers
                                         // finished buf[c&1] (chunk c-2) already
            #pragma unroll
            for (int r = 0; r < 4; ++r) cur[r] = nxt[r];
        }
    } else {
        // ---- consumer: serial dual-threshold scan, one d per thread ----
        const int ctid = tid - 256;      // 0..255
        float* op = out + base + ctid;
        float v = 0.0f;

        #pragma unroll 1
        for (int c = 0; c < CHUNKS; ++c) {
            __syncthreads();             // matches producer barrier c
            const int pp = c & 1;
            float* opc = op + (size_t)c * CT * D_DIM;
            #pragma unroll
            for (int u = 0; u < CT; ++u) {
                float r = lds_r[pp][u][ctid];
                v = __builtin_fmaf(r, 0.01f, v);        // v += r*DT
                float sp = (v >= 1.0f)  ? 1.0f : 0.0f;
                float sn = (v <= -1.0f) ? 1.0f : 0.0f;
                v = (v - sp) + sn;                      // subtractive reset (exact)
                opc[(size_t)u * D_DIM] = (sp - sn) * 100.0f;  // ±100 exactly
            }
        }
    }
}

extern "C" void kernel_launch(void* const* d_in, const int* in_sizes, int n_in,
                              void* d_out, int out_size, void* d_ws, size_t ws_size,
                              hipStream_t stream) {
    const float* in = (const float*)d_in[0];
    float* out = (float*)d_out;
    dim3 block(TPB);
    dim3 grid(B_DIM * (D_DIM / DSLICE));  // 256 blocks -> 1 per CU, 8 waves/CU
    spike_scan_kernel<<<grid, block, 0, stream>>>(in, out);
}